// Round 7
// baseline (390.451 us; speedup 1.0000x reference)
//
#include <hip/hip_runtime.h>
#include <math.h>

#define NG 512
#define NP 128
#define HID 64
#define KNN 24
#define NTOT (NG*NP)

typedef __attribute__((ext_vector_type(8)))  short  short8;
typedef __attribute__((ext_vector_type(16))) float  floatx16;

__device__ __forceinline__ float elu_f(float v) { return v > 0.0f ? v : expm1f(v); }

__device__ __forceinline__ void split_bf16(float x, unsigned short& hb, unsigned short& lb) {
    unsigned u = __float_as_uint(x);
    unsigned h = (u + 0x7FFFu + ((u >> 16) & 1u)) >> 16;
    hb = (unsigned short)h;
    float hf = __uint_as_float(h << 16);
    float lo = x - hf;
    unsigned v = __float_as_uint(lo);
    lb = (unsigned short)((v + 0x7FFFu + ((v >> 16) & 1u)) >> 16);
}
__device__ __forceinline__ unsigned short bf_rne(float x) {
    unsigned u = __float_as_uint(x);
    return (unsigned short)((u + 0x7FFFu + ((u >> 16) & 1u)) >> 16);
}
__device__ __forceinline__ float bf_lo(unsigned u) { return __uint_as_float(u << 16); }
__device__ __forceinline__ float bf_hi(unsigned u) { return __uint_as_float(u & 0xFFFF0000u); }

// XOR-swizzled hilo accessor: row = 16 chunks of 16B (hi ch 0..7, lo ch 8..15).
__device__ __forceinline__ unsigned short* hchunk(unsigned short* base, int row, int ch) {
    return base + (((row << 4) + (ch ^ (row & 15))) << 3);
}
__device__ __forceinline__ const unsigned short* hchunk(const unsigned short* base, int row, int ch) {
    return base + (((row << 4) + (ch ^ (row & 15))) << 3);
}

// bitonic sort 8 ascending
__device__ __forceinline__ void sort8_asc(unsigned* y) {
    #pragma unroll
    for (int k = 2; k <= 8; k <<= 1)
        #pragma unroll
        for (int j = k >> 1; j > 0; j >>= 1)
            #pragma unroll
            for (int i = 0; i < 8; ++i) {
                const int l = i ^ j;
                if (l > i) {
                    const bool up = ((i & k) == 0);
                    const unsigned a = y[i], b = y[l];
                    const unsigned mn = a < b ? a : b;
                    const unsigned mx = a < b ? b : a;
                    y[i] = up ? mn : mx;
                    y[l] = up ? mx : mn;
                }
            }
}

// x[0..23] asc ++ x[24..31] desc (bitonic) -> keep smallest 24 sorted
__device__ __forceinline__ void merge_top24(unsigned* x) {
    #pragma unroll
    for (int d = 16; d > 0; d >>= 1)
        #pragma unroll
        for (int i = 0; i < 32; ++i)
            if (!(i & d) && i < 24) {
                const int l = i | d;
                const unsigned a = x[i], b = x[l];
                x[i] = a < b ? a : b;
                x[l] = a < b ? b : a;
            }
}

// ---------------- pack weights into MFMA-B-fragment-ready hi/lo bf16 layout ----------------
__global__ __launch_bounds__(256) void pack_w(
    const float* __restrict__ wc1, const float* __restrict__ wc2, const float* __restrict__ wc3,
    const float* __restrict__ we2,
    unsigned short* __restrict__ wp)
{
    const int n = blockIdx.x*256 + threadIdx.x;      // 0..28671
    if (n < 24576) {
        const int layer = n >> 13;
        const int r = n & 8191;
        const int e = r & 7, j = (r >> 3) & 127, ch = r >> 10;
        const int k = (ch >> 1)*16 + (ch & 1)*8 + e;
        const float* wc = (layer == 0) ? wc1 : ((layer == 1) ? wc2 : wc3);
        float w;
        if (j < 64) w = wc[k*64 + j] - wc[(k+64)*64 + j];
        else        w = wc[(k+64)*64 + (j-64)];
        unsigned short hb, lb;
        split_bf16(w, hb, lb);
        unsigned short* base = wp + layer*16384;
        base[r] = hb;
        base[8192 + r] = lb;
    } else if (n < 24576 + 4096) {
        const int m = n - 24576;
        const int e = m & 7, col = (m >> 3) & 63, ch = m >> 9;
        const int k = (ch >> 1)*16 + (ch & 1)*8 + e;
        unsigned short hb, lb;
        split_bf16(we2[k*64 + col], hb, lb);
        unsigned short* base = wp + 49152;
        base[m] = hb;
        base[4096 + m] = lb;
    }
}

// ---------------- single fused kernel: encoder + 3 dynamic-edge-conv layers + pooling ----------------
// 512 threads (8 waves), one graph per block.
// Arena (53760 B -> 3 blocks/CU):
//   keys  [128][34] u32 @0      (17408; aliases: prologue staging, bs bf16[128][64] in ab/agg phase)
//   nnidx [128][6]  u32 @17408  ( 3072; aliases pool8[8][64] f32 in final epilogue)
//   hilo  swizzled bf16 @20480  (32768)
//   sqs   [128] f32 @53248      (  512)
__global__ __launch_bounds__(512, 6) void conv_all(
    const float* __restrict__ x,
    const unsigned short* __restrict__ wp,
    const float* __restrict__ bc1, const float* __restrict__ bc2, const float* __restrict__ bc3,
    const float* __restrict__ we1, const float* __restrict__ be1,
    const unsigned short* __restrict__ we2p, const float* __restrict__ be2,
    float* __restrict__ ag_all, float* __restrict__ pooled_out, float* __restrict__ out_batch)
{
    __shared__ __align__(16) char arena[53760];
    unsigned*        keys  = (unsigned*)arena;
    unsigned*        nnidx = (unsigned*)(arena + 17408);
    unsigned short*  hilo  = (unsigned short*)(arena + 20480);
    float*           sqs   = (float*)(arena + 53248);

    const int g = blockIdx.x;
    const int t = threadIdx.x;
    const int w = t >> 6, lane = t & 63;
    const int lj = lane & 31, half = lane >> 5;
    const int rt = w & 3, wg = w >> 2;
    const int i2 = t & 127, s4 = t >> 7;
    float* __restrict__ ag = ag_all + (size_t)g * (NP*HID);

    // ================= encoder prologue =================
    {
        float* w1s = (float*)arena;            // [4][64]
        float* b1v = (float*)(arena + 1024);   // [64]
        float* b2v = (float*)(arena + 1280);   // [64]
        if (t < 256) w1s[t] = we1[t];
        else if (t < 320) b1v[t-256] = be1[t-256];
        else if (t < 384) b2v[t-320] = be2[t-320];
        if (t < 128) out_batch[(size_t)g*128 + t] = (float)g;
        __syncthreads();

        // layer 1: n = node, fh = col-quarter (16 cols)
        const int n = t & 127, fh = t >> 7, f0 = fh*16;
        const float4 xv = ((const float4*)x)[g*128 + n];
        float acc1[16];
        #pragma unroll
        for (int q = 0; q < 4; ++q) {
            const float4 b4 = *(const float4*)(b1v + f0 + q*4);
            acc1[q*4+0] = b4.x; acc1[q*4+1] = b4.y; acc1[q*4+2] = b4.z; acc1[q*4+3] = b4.w;
        }
        #pragma unroll
        for (int k = 0; k < 4; ++k) {
            const float xk_ = (k == 0) ? xv.x : (k == 1) ? xv.y : (k == 2) ? xv.z : xv.w;
            #pragma unroll
            for (int q = 0; q < 4; ++q) {
                const float4 w4 = *(const float4*)(w1s + k*64 + f0 + q*4);
                acc1[q*4+0] = fmaf(xk_, w4.x, acc1[q*4+0]);
                acc1[q*4+1] = fmaf(xk_, w4.y, acc1[q*4+1]);
                acc1[q*4+2] = fmaf(xk_, w4.z, acc1[q*4+2]);
                acc1[q*4+3] = fmaf(xk_, w4.w, acc1[q*4+3]);
            }
        }
        unsigned hu[8], lu[8];
        #pragma unroll
        for (int e = 0; e < 8; ++e) {
            const float v0 = elu_f(acc1[2*e]), v1 = elu_f(acc1[2*e+1]);
            unsigned short h0, l0, h1, l1;
            split_bf16(v0, h0, l0); split_bf16(v1, h1, l1);
            hu[e] = (unsigned)h0 | ((unsigned)h1 << 16);
            lu[e] = (unsigned)l0 | ((unsigned)l1 << 16);
        }
        *(uint4*)hchunk(hilo, n, fh*2)       = make_uint4(hu[0], hu[1], hu[2], hu[3]);
        *(uint4*)hchunk(hilo, n, fh*2 + 1)   = make_uint4(hu[4], hu[5], hu[6], hu[7]);
        *(uint4*)hchunk(hilo, n, 8 + fh*2)   = make_uint4(lu[0], lu[1], lu[2], lu[3]);
        *(uint4*)hchunk(hilo, n, 8 + fh*2+1) = make_uint4(lu[4], lu[5], lu[6], lu[7]);
        __syncthreads();

        // layer 2 via MFMA: 8 tiles = (rt, jt2=wg)
        const int jt2 = wg;
        floatx16 acc = {0.f,0.f,0.f,0.f,0.f,0.f,0.f,0.f,0.f,0.f,0.f,0.f,0.f,0.f,0.f,0.f};
        #pragma unroll
        for (int p = 0; p < 3; ++p) {
            const int aSel = (p == 2) ? 8 : 0;
            const int part = (p == 1) ? 1 : 0;
            short8 af[4], bf4[4];
            #pragma unroll
            for (int c = 0; c < 4; ++c) {
                af[c]  = *(const short8*)hchunk(hilo, rt*32 + lj, aSel + c*2 + half);
                bf4[c] = *(const short8*)((const short*)we2p + part*4096 + (((c*2 + half)*64) + jt2*32 + lj)*8);
            }
            #pragma unroll
            for (int c = 0; c < 4; ++c) acc = __builtin_amdgcn_mfma_f32_32x32x16_bf16(af[c], bf4[c], acc, 0, 0, 0);
        }
        const int col = jt2*32 + lj;
        const float bias = b2v[col];
        __syncthreads();   // all layer-2 hilo reads done before overwrite
        #pragma unroll
        for (int reg = 0; reg < 16; ++reg) {
            const int row = (reg & 3) + 8*(reg >> 2) + 4*half + rt*32;
            const float v = elu_f(acc[reg] + bias);
            unsigned short hb, lb;
            split_bf16(v, hb, lb);
            *(hchunk(hilo, row, col >> 3) + (col & 7))       = hb;
            *(hchunk(hilo, row, 8 + (col >> 3)) + (col & 7)) = lb;
        }
        __syncthreads();

        // sq read-back: r = node, cq = col-quarter
        const int r = t >> 2, cq = t & 3, c0 = cq*2;
        const uint4 h0 = *(const uint4*)hchunk(hilo, r, c0);
        const uint4 h1 = *(const uint4*)hchunk(hilo, r, c0+1);
        const uint4 l0 = *(const uint4*)hchunk(hilo, r, 8+c0);
        const uint4 l1 = *(const uint4*)hchunk(hilo, r, 8+c0+1);
        float s = 0.0f;
        const unsigned hh[8] = {h0.x,h0.y,h0.z,h0.w,h1.x,h1.y,h1.z,h1.w};
        const unsigned ll[8] = {l0.x,l0.y,l0.z,l0.w,l1.x,l1.y,l1.z,l1.w};
        #pragma unroll
        for (int e = 0; e < 8; ++e) {
            const float va = bf_lo(hh[e]) + bf_lo(ll[e]);
            const float vb = bf_hi(hh[e]) + bf_hi(ll[e]);
            s = fmaf(va, va, s); s = fmaf(vb, vb, s);
        }
        s += __shfl_xor(s, 1);
        s += __shfl_xor(s, 2);
        if (cq == 0) sqs[r] = s;
        __syncthreads();
    }

    // ================= 3 conv layers =================
    #pragma unroll 1
    for (int L = 0; L < 3; ++L) {
        const unsigned short* wpl = wp + L*16384;
        const float* bcl = (L == 0) ? bc1 : (L == 1) ? bc2 : bc3;

        // ---- Gram rounds + batched-bitonic top-k ----
        unsigned xk[32];
        #pragma unroll
        for (int s = 0; s < 24; ++s) xk[s] = 0xFFFFFFFFu;

        #pragma unroll 1
        for (int jt = 0; jt < 4; ++jt) {
            if (wg == (jt & 1)) {
                floatx16 acc = {0.f,0.f,0.f,0.f,0.f,0.f,0.f,0.f,0.f,0.f,0.f,0.f,0.f,0.f,0.f,0.f};
                #pragma unroll
                for (int p = 0; p < 3; ++p) {
                    const int aSel = (p == 2) ? 8 : 0;
                    const int bSel = (p == 1) ? 8 : 0;
                    short8 af[4], bf4[4];
                    #pragma unroll
                    for (int c = 0; c < 4; ++c) {
                        af[c]  = *(const short8*)hchunk(hilo, rt*32 + lj, aSel + c*2 + half);
                        bf4[c] = *(const short8*)hchunk(hilo, jt*32 + lj, bSel + c*2 + half);
                    }
                    #pragma unroll
                    for (int c = 0; c < 4; ++c) acc = __builtin_amdgcn_mfma_f32_32x32x16_bf16(af[c], bf4[c], acc, 0, 0, 0);
                }
                const unsigned jg = (unsigned)(jt*32 + lj);
                const float sqj = sqs[jg];
                #pragma unroll
                for (int reg = 0; reg < 16; ++reg) {
                    const int i = (reg & 3) + 8*(reg >> 2) + 4*half + rt*32;
                    float d = fmaf(-2.0f, acc[reg], sqs[i] + sqj);
                    d = fmaxf(d, 0.0f);
                    keys[i*34 + lj] = (__float_as_uint(d) & 0xFFFFFF80u) | jg;
                }
            }
            __syncthreads();
            {
                const unsigned* kr = keys + i2*34 + s4*8;
                const uint4 k0 = *(const uint4*)kr;
                const uint4 k1 = *(const uint4*)(kr + 4);
                unsigned y[8] = {k0.x, k0.y, k0.z, k0.w, k1.x, k1.y, k1.z, k1.w};
                sort8_asc(y);
                #pragma unroll
                for (int e = 0; e < 8; ++e) xk[24+e] = y[7-e];
                merge_top24(xk);
            }
            __syncthreads();
        }

        // ---- merge the 4 per-row lists into s4==0, emit nnidx ----
        #pragma unroll 1
        for (int src = 1; src < 4; ++src) {
            if (s4 == src) {
                #pragma unroll
                for (int e = 0; e < 24; ++e) keys[i2*34 + 8 + e] = xk[e];
            }
            __syncthreads();
            if (s4 == 0) {
                #pragma unroll 1
                for (int b = 0; b < 3; ++b) {
                    #pragma unroll
                    for (int e = 0; e < 8; ++e) xk[24+e] = keys[i2*34 + 8 + b*8 + (7-e)];
                    merge_top24(xk);
                }
            }
            __syncthreads();
        }
        if (s4 == 0) {
            #pragma unroll
            for (int c = 0; c < 6; ++c)
                nnidx[i2*6 + c] = (xk[c*4] & 127u) | ((xk[c*4+1] & 127u) << 8)
                                | ((xk[c*4+2] & 127u) << 16) | ((xk[c*4+3] & 127u) << 24);
        }
        __syncthreads();   // keys dead -> bs may overwrite; nnidx visible

        // ---- ab-GEMM: waves 0-3 -> a (global, +bias), waves 4-7 -> b (LDS bf16 [128][64]) ----
        unsigned short* bs = (unsigned short*)arena;
        {
            short8 afr[8];
            #pragma unroll
            for (int sel = 0; sel < 2; ++sel)
                #pragma unroll
                for (int c = 0; c < 4; ++c)
                    afr[sel*4+c] = *(const short8*)hchunk(hilo, rt*32 + lj, sel*8 + c*2 + half);

            #pragma unroll 1
            for (int q2 = 0; q2 < 2; ++q2) {
                const int jt = wg*2 + q2;
                short8 bfr[8];
                #pragma unroll
                for (int part = 0; part < 2; ++part)
                    #pragma unroll
                    for (int c = 0; c < 4; ++c)
                        bfr[part*4+c] = *(const short8*)((const short*)wpl + part*8192 + (((c*2 + half)*128) + jt*32 + lj)*8);
                floatx16 acc = {0.f,0.f,0.f,0.f,0.f,0.f,0.f,0.f,0.f,0.f,0.f,0.f,0.f,0.f,0.f,0.f};
                #pragma unroll
                for (int c = 0; c < 4; ++c) acc = __builtin_amdgcn_mfma_f32_32x32x16_bf16(afr[c],   bfr[c],   acc, 0, 0, 0);
                #pragma unroll
                for (int c = 0; c < 4; ++c) acc = __builtin_amdgcn_mfma_f32_32x32x16_bf16(afr[c],   bfr[4+c], acc, 0, 0, 0);
                #pragma unroll
                for (int c = 0; c < 4; ++c) acc = __builtin_amdgcn_mfma_f32_32x32x16_bf16(afr[4+c], bfr[c],   acc, 0, 0, 0);

                if (wg == 0) {
                    const int col = jt*32 + lj;
                    const float bias = bcl[col];
                    #pragma unroll
                    for (int reg = 0; reg < 16; ++reg) {
                        const int row = (reg & 3) + 8*(reg >> 2) + 4*half + rt*32;
                        ag[(size_t)row*64 + col] = acc[reg] + bias;
                    }
                } else {
                    const int colb = q2*32 + lj;
                    #pragma unroll
                    for (int reg = 0; reg < 16; ++reg) {
                        const int row = (reg & 3) + 8*(reg >> 2) + 4*half + rt*32;
                        bs[row*64 + colb] = bf_rne(acc[reg]);
                    }
                }
            }
        }
        __syncthreads();   // bs/ag ready; hilo reads done -> may be rewritten

        // ---- aggregation: out = elu(a + max_nn b); emit next hilo+sq, or pooled on last layer ----
        // lane = (rsub 0..7) x (fq 0..7): 8 rows/wave/iter, 8 features per lane (one uint4 per nbr)
        {
            const int rsub = lane >> 3, fq = lane & 7;
            float psum[8] = {0.f,0.f,0.f,0.f,0.f,0.f,0.f,0.f};
            #pragma unroll 1
            for (int it = 0; it < 2; ++it) {
                const int row = w*16 + it*8 + rsub;
                float m[8];
                #pragma unroll
                for (int e = 0; e < 8; ++e) m[e] = -3e38f;
                #pragma unroll
                for (int c = 0; c < 6; ++c) {
                    const unsigned pk = nnidx[row*6 + c];
                    #pragma unroll
                    for (int e2 = 0; e2 < 4; ++e2) {
                        const int j = (pk >> (8*e2)) & 127;
                        const uint4 bb = *(const uint4*)(bs + j*64 + fq*8);
                        m[0] = fmaxf(m[0], bf_lo(bb.x)); m[1] = fmaxf(m[1], bf_hi(bb.x));
                        m[2] = fmaxf(m[2], bf_lo(bb.y)); m[3] = fmaxf(m[3], bf_hi(bb.y));
                        m[4] = fmaxf(m[4], bf_lo(bb.z)); m[5] = fmaxf(m[5], bf_hi(bb.z));
                        m[6] = fmaxf(m[6], bf_lo(bb.w)); m[7] = fmaxf(m[7], bf_hi(bb.w));
                    }
                }
                const float4 a0 = *(const float4*)(ag + (size_t)row*64 + fq*8);
                const float4 a1 = *(const float4*)(ag + (size_t)row*64 + fq*8 + 4);
                float o[8];
                o[0] = elu_f(a0.x + m[0]); o[1] = elu_f(a0.y + m[1]);
                o[2] = elu_f(a0.z + m[2]); o[3] = elu_f(a0.w + m[3]);
                o[4] = elu_f(a1.x + m[4]); o[5] = elu_f(a1.y + m[5]);
                o[6] = elu_f(a1.z + m[6]); o[7] = elu_f(a1.w + m[7]);

                if (L < 2) {
                    unsigned hu[4], lu[4];
                    #pragma unroll
                    for (int e = 0; e < 4; ++e) {
                        unsigned short h0, l0, h1, l1;
                        split_bf16(o[2*e], h0, l0); split_bf16(o[2*e+1], h1, l1);
                        hu[e] = (unsigned)h0 | ((unsigned)h1 << 16);
                        lu[e] = (unsigned)l0 | ((unsigned)l1 << 16);
                    }
                    *(uint4*)hchunk(hilo, row, fq)     = make_uint4(hu[0], hu[1], hu[2], hu[3]);
                    *(uint4*)hchunk(hilo, row, 8 + fq) = make_uint4(lu[0], lu[1], lu[2], lu[3]);
                    float sp = 0.f;
                    #pragma unroll
                    for (int e = 0; e < 8; ++e) sp = fmaf(o[e], o[e], sp);
                    sp += __shfl_xor(sp, 1);
                    sp += __shfl_xor(sp, 2);
                    sp += __shfl_xor(sp, 4);
                    if (fq == 0) sqs[row] = sp;
                } else {
                    #pragma unroll
                    for (int e = 0; e < 8; ++e) psum[e] += o[e];
                }
            }
            if (L < 2) {
                __syncthreads();   // next layer sees new hilo + sqs
            } else {
                // reduce over rows (lanes with same fq): xor 8,16,32
                #pragma unroll
                for (int e = 0; e < 8; ++e) {
                    psum[e] += __shfl_xor(psum[e], 8);
                    psum[e] += __shfl_xor(psum[e], 16);
                    psum[e] += __shfl_xor(psum[e], 32);
                }
                __syncthreads();   // nnidx reads done -> pool8 may alias
                float* pool8 = (float*)(arena + 17408);   // [8][64]
                if (rsub == 0) {
                    *(float4*)(pool8 + w*64 + fq*8)     = make_float4(psum[0], psum[1], psum[2], psum[3]);
                    *(float4*)(pool8 + w*64 + fq*8 + 4) = make_float4(psum[4], psum[5], psum[6], psum[7]);
                }
                __syncthreads();
                if (t < 64) {
                    float s = 0.0f;
                    #pragma unroll
                    for (int k = 0; k < 8; ++k) s += pool8[k*64 + t];
                    pooled_out[(size_t)g*64 + t] = s;
                }
            }
        }
    }
}

// ---------------- head: 5-layer MLP on pooled[512][64] ----------------
__global__ __launch_bounds__(64) void head_kernel(
    const float* __restrict__ pooled_in,
    const float* __restrict__ wo1, const float* __restrict__ bo1,
    const float* __restrict__ wo2, const float* __restrict__ bo2,
    const float* __restrict__ wo3, const float* __restrict__ bo3,
    const float* __restrict__ wo4, const float* __restrict__ bo4,
    const float* __restrict__ wo5, const float* __restrict__ bo5,
    float* __restrict__ outp)
{
    __shared__ float pooled[64];
    __shared__ float o1[64];
    __shared__ float o2[32];
    __shared__ float o3[32];
    __shared__ float o4[8];
    const int g = blockIdx.x, t = threadIdx.x;

    pooled[t] = pooled_in[(size_t)g*64 + t];
    {
        float acc = bo1[t];
        #pragma unroll
        for (int k = 0; k < 64; ++k) acc = fmaf(pooled[k], wo1[k*64 + t], acc);
        o1[t] = elu_f(acc);
    }
    if (t < 32) {
        float acc = bo2[t];
        #pragma unroll
        for (int k = 0; k < 64; ++k) acc = fmaf(o1[k], wo2[k*32 + t], acc);
        o2[t] = elu_f(acc);
    }
    if (t < 32) {
        float acc = bo3[t];
        #pragma unroll
        for (int k = 0; k < 32; ++k) acc = fmaf(o2[k], wo3[k*32 + t], acc);
        o3[t] = elu_f(acc);
    }
    if (t < 8) {
        float acc = bo4[t];
        #pragma unroll
        for (int k = 0; k < 32; ++k) acc = fmaf(o3[k], wo4[k*8 + t], acc);
        o4[t] = elu_f(acc);
    }
    if (t == 0) {
        float acc = bo5[0];
        #pragma unroll
        for (int k = 0; k < 8; ++k) acc = fmaf(o4[k], wo5[k], acc);
        outp[g] = acc;
    }
}

extern "C" void kernel_launch(void* const* d_in, const int* in_sizes, int n_in,
                              void* d_out, int out_size, void* d_ws, size_t ws_size,
                              hipStream_t stream) {
    const float* x_pf = (const float*)d_in[0];
    const float* we1 = (const float*)d_in[2];
    const float* be1 = (const float*)d_in[3];
    const float* we2 = (const float*)d_in[4];
    const float* be2 = (const float*)d_in[5];
    const float* wc1 = (const float*)d_in[6];
    const float* bc1 = (const float*)d_in[7];
    const float* wc2 = (const float*)d_in[8];
    const float* bc2 = (const float*)d_in[9];
    const float* wc3 = (const float*)d_in[10];
    const float* bc3 = (const float*)d_in[11];
    const float* wo1 = (const float*)d_in[12];
    const float* bo1 = (const float*)d_in[13];
    const float* wo2 = (const float*)d_in[14];
    const float* bo2 = (const float*)d_in[15];
    const float* wo3 = (const float*)d_in[16];
    const float* bo3 = (const float*)d_in[17];
    const float* wo4 = (const float*)d_in[18];
    const float* bo4 = (const float*)d_in[19];
    const float* wo5 = (const float*)d_in[20];
    const float* bo5 = (const float*)d_in[21];

    float* out = (float*)d_out;           // [0:512) outputs, [512:) batch ids (as float)
    char* ws = (char*)d_ws;
    float* abuf   = (float*)(ws);                                  // 16 MB
    float* pooled = (float*)(ws + (size_t)16*1024*1024);           // 128 KB
    unsigned short* wpack = (unsigned short*)(ws + (size_t)17*1024*1024);  // 112 KB

    pack_w<<<112, 256, 0, stream>>>(wc1, wc2, wc3, we2, wpack);

    conv_all<<<NG, 512, 0, stream>>>(x_pf, wpack, bc1, bc2, bc3,
        we1, be1, wpack + 49152, be2, abuf, pooled, out + NG);

    head_kernel<<<NG, 64, 0, stream>>>(pooled, wo1, bo1, wo2, bo2, wo3, bo3, wo4, bo4, wo5, bo5, out);
}

// Round 8
// 193.952 us; speedup vs baseline: 2.0131x; 2.0131x over previous
//
#include <hip/hip_runtime.h>
#include <math.h>

#define NG 512
#define NP 128
#define HID 64
#define KNN 24
#define NTOT (NG*NP)

typedef __attribute__((ext_vector_type(8)))  short  short8;
typedef __attribute__((ext_vector_type(16))) float  floatx16;

__device__ __forceinline__ float elu_f(float v) { return v > 0.0f ? v : expm1f(v); }

__device__ __forceinline__ void split_bf16(float x, unsigned short& hb, unsigned short& lb) {
    unsigned u = __float_as_uint(x);
    unsigned h = (u + 0x7FFFu + ((u >> 16) & 1u)) >> 16;
    hb = (unsigned short)h;
    float hf = __uint_as_float(h << 16);
    float lo = x - hf;
    unsigned v = __float_as_uint(lo);
    lb = (unsigned short)((v + 0x7FFFu + ((v >> 16) & 1u)) >> 16);
}
__device__ __forceinline__ unsigned short bf_rne(float x) {
    unsigned u = __float_as_uint(x);
    return (unsigned short)((u + 0x7FFFu + ((u >> 16) & 1u)) >> 16);
}
__device__ __forceinline__ float bf_lo(unsigned u) { return __uint_as_float(u << 16); }
__device__ __forceinline__ float bf_hi(unsigned u) { return __uint_as_float(u & 0xFFFF0000u); }

// XOR-swizzled hilo accessor: row = 16 chunks of 16B (hi ch 0..7, lo ch 8..15).
__device__ __forceinline__ unsigned short* hchunk(unsigned short* base, int row, int ch) {
    return base + (((row << 4) + (ch ^ (row & 15))) << 3);
}
__device__ __forceinline__ const unsigned short* hchunk(const unsigned short* base, int row, int ch) {
    return base + (((row << 4) + (ch ^ (row & 15))) << 3);
}

// bitonic sort 8 ascending
__device__ __forceinline__ void sort8_asc(unsigned* y) {
    #pragma unroll
    for (int k = 2; k <= 8; k <<= 1)
        #pragma unroll
        for (int j = k >> 1; j > 0; j >>= 1)
            #pragma unroll
            for (int i = 0; i < 8; ++i) {
                const int l = i ^ j;
                if (l > i) {
                    const bool up = ((i & k) == 0);
                    const unsigned a = y[i], b = y[l];
                    const unsigned mn = a < b ? a : b;
                    const unsigned mx = a < b ? b : a;
                    y[i] = up ? mn : mx;
                    y[l] = up ? mx : mn;
                }
            }
}

// x[0..23] asc ++ x[24..31] desc (bitonic) -> keep smallest 24 sorted
__device__ __forceinline__ void merge_top24(unsigned* x) {
    #pragma unroll
    for (int d = 16; d > 0; d >>= 1)
        #pragma unroll
        for (int i = 0; i < 32; ++i)
            if (!(i & d) && i < 24) {
                const int l = i | d;
                const unsigned a = x[i], b = x[l];
                x[i] = a < b ? a : b;
                x[l] = a < b ? b : a;
            }
}

// ---------------- pack weights into MFMA-B-fragment-ready hi/lo bf16 layout ----------------
__global__ __launch_bounds__(256) void pack_w(
    const float* __restrict__ wc1, const float* __restrict__ wc2, const float* __restrict__ wc3,
    const float* __restrict__ we2,
    unsigned short* __restrict__ wp)
{
    const int n = blockIdx.x*256 + threadIdx.x;      // 0..28671
    if (n < 24576) {
        const int layer = n >> 13;
        const int r = n & 8191;
        const int e = r & 7, j = (r >> 3) & 127, ch = r >> 10;
        const int k = (ch >> 1)*16 + (ch & 1)*8 + e;
        const float* wc = (layer == 0) ? wc1 : ((layer == 1) ? wc2 : wc3);
        float w;
        if (j < 64) w = wc[k*64 + j] - wc[(k+64)*64 + j];
        else        w = wc[(k+64)*64 + (j-64)];
        unsigned short hb, lb;
        split_bf16(w, hb, lb);
        unsigned short* base = wp + layer*16384;
        base[r] = hb;
        base[8192 + r] = lb;
    } else if (n < 24576 + 4096) {
        const int m = n - 24576;
        const int e = m & 7, col = (m >> 3) & 63, ch = m >> 9;
        const int k = (ch >> 1)*16 + (ch & 1)*8 + e;
        unsigned short hb, lb;
        split_bf16(we2[k*64 + col], hb, lb);
        unsigned short* base = wp + 49152;
        base[m] = hb;
        base[4096 + m] = lb;
    }
}

// ---------------- single fused kernel: encoder + 3 dynamic-edge-conv layers + pooling ----------------
// 512 threads (8 waves), one graph per block.
// Arena (53760 B -> LDS permits 3 blocks/CU):
//   keys  [128][34] u32 @0      (17408; aliases: prologue staging, bs bf16[128][64] in ab/agg phase)
//   nnidx [128][6]  u32 @17408  ( 3072; aliases pool8[8][64] f32 in final epilogue)
//   hilo  swizzled bf16 @20480  (32768)
//   sqs   [128] f32 @53248      (  512)
// launch_bounds min-waves stays 4: (512,6) capped VGPR at 40 -> xk[32] spilled,
// 775 MB scratch traffic/dispatch (R7). 64-VGPR codegen already allows 6 waves/SIMD;
// occupancy is LDS-limited, so the cap must not bind the allocator.
__global__ __launch_bounds__(512, 4) void conv_all(
    const float* __restrict__ x,
    const unsigned short* __restrict__ wp,
    const float* __restrict__ bc1, const float* __restrict__ bc2, const float* __restrict__ bc3,
    const float* __restrict__ we1, const float* __restrict__ be1,
    const unsigned short* __restrict__ we2p, const float* __restrict__ be2,
    float* __restrict__ ag_all, float* __restrict__ pooled_out, float* __restrict__ out_batch)
{
    __shared__ __align__(16) char arena[53760];
    unsigned*        keys  = (unsigned*)arena;
    unsigned*        nnidx = (unsigned*)(arena + 17408);
    unsigned short*  hilo  = (unsigned short*)(arena + 20480);
    float*           sqs   = (float*)(arena + 53248);

    const int g = blockIdx.x;
    const int t = threadIdx.x;
    const int w = t >> 6, lane = t & 63;
    const int lj = lane & 31, half = lane >> 5;
    const int rt = w & 3, wg = w >> 2;
    const int i2 = t & 127, s4 = t >> 7;
    float* __restrict__ ag = ag_all + (size_t)g * (NP*HID);

    // ================= encoder prologue =================
    {
        float* w1s = (float*)arena;            // [4][64]
        float* b1v = (float*)(arena + 1024);   // [64]
        float* b2v = (float*)(arena + 1280);   // [64]
        if (t < 256) w1s[t] = we1[t];
        else if (t < 320) b1v[t-256] = be1[t-256];
        else if (t < 384) b2v[t-320] = be2[t-320];
        if (t < 128) out_batch[(size_t)g*128 + t] = (float)g;
        __syncthreads();

        // layer 1: n = node, fh = col-quarter (16 cols)
        const int n = t & 127, fh = t >> 7, f0 = fh*16;
        const float4 xv = ((const float4*)x)[g*128 + n];
        float acc1[16];
        #pragma unroll
        for (int q = 0; q < 4; ++q) {
            const float4 b4 = *(const float4*)(b1v + f0 + q*4);
            acc1[q*4+0] = b4.x; acc1[q*4+1] = b4.y; acc1[q*4+2] = b4.z; acc1[q*4+3] = b4.w;
        }
        #pragma unroll
        for (int k = 0; k < 4; ++k) {
            const float xk_ = (k == 0) ? xv.x : (k == 1) ? xv.y : (k == 2) ? xv.z : xv.w;
            #pragma unroll
            for (int q = 0; q < 4; ++q) {
                const float4 w4 = *(const float4*)(w1s + k*64 + f0 + q*4);
                acc1[q*4+0] = fmaf(xk_, w4.x, acc1[q*4+0]);
                acc1[q*4+1] = fmaf(xk_, w4.y, acc1[q*4+1]);
                acc1[q*4+2] = fmaf(xk_, w4.z, acc1[q*4+2]);
                acc1[q*4+3] = fmaf(xk_, w4.w, acc1[q*4+3]);
            }
        }
        unsigned hu[8], lu[8];
        #pragma unroll
        for (int e = 0; e < 8; ++e) {
            const float v0 = elu_f(acc1[2*e]), v1 = elu_f(acc1[2*e+1]);
            unsigned short h0, l0, h1, l1;
            split_bf16(v0, h0, l0); split_bf16(v1, h1, l1);
            hu[e] = (unsigned)h0 | ((unsigned)h1 << 16);
            lu[e] = (unsigned)l0 | ((unsigned)l1 << 16);
        }
        *(uint4*)hchunk(hilo, n, fh*2)       = make_uint4(hu[0], hu[1], hu[2], hu[3]);
        *(uint4*)hchunk(hilo, n, fh*2 + 1)   = make_uint4(hu[4], hu[5], hu[6], hu[7]);
        *(uint4*)hchunk(hilo, n, 8 + fh*2)   = make_uint4(lu[0], lu[1], lu[2], lu[3]);
        *(uint4*)hchunk(hilo, n, 8 + fh*2+1) = make_uint4(lu[4], lu[5], lu[6], lu[7]);
        __syncthreads();

        // layer 2 via MFMA: 8 tiles = (rt, jt2=wg)
        const int jt2 = wg;
        floatx16 acc = {0.f,0.f,0.f,0.f,0.f,0.f,0.f,0.f,0.f,0.f,0.f,0.f,0.f,0.f,0.f,0.f};
        #pragma unroll
        for (int p = 0; p < 3; ++p) {
            const int aSel = (p == 2) ? 8 : 0;
            const int part = (p == 1) ? 1 : 0;
            short8 af[4], bf4[4];
            #pragma unroll
            for (int c = 0; c < 4; ++c) {
                af[c]  = *(const short8*)hchunk(hilo, rt*32 + lj, aSel + c*2 + half);
                bf4[c] = *(const short8*)((const short*)we2p + part*4096 + (((c*2 + half)*64) + jt2*32 + lj)*8);
            }
            #pragma unroll
            for (int c = 0; c < 4; ++c) acc = __builtin_amdgcn_mfma_f32_32x32x16_bf16(af[c], bf4[c], acc, 0, 0, 0);
        }
        const int col = jt2*32 + lj;
        const float bias = b2v[col];
        __syncthreads();   // all layer-2 hilo reads done before overwrite
        #pragma unroll
        for (int reg = 0; reg < 16; ++reg) {
            const int row = (reg & 3) + 8*(reg >> 2) + 4*half + rt*32;
            const float v = elu_f(acc[reg] + bias);
            unsigned short hb, lb;
            split_bf16(v, hb, lb);
            *(hchunk(hilo, row, col >> 3) + (col & 7))       = hb;
            *(hchunk(hilo, row, 8 + (col >> 3)) + (col & 7)) = lb;
        }
        __syncthreads();

        // sq read-back: r = node, cq = col-quarter
        const int r = t >> 2, cq = t & 3, c0 = cq*2;
        const uint4 h0 = *(const uint4*)hchunk(hilo, r, c0);
        const uint4 h1 = *(const uint4*)hchunk(hilo, r, c0+1);
        const uint4 l0 = *(const uint4*)hchunk(hilo, r, 8+c0);
        const uint4 l1 = *(const uint4*)hchunk(hilo, r, 8+c0+1);
        float s = 0.0f;
        const unsigned hh[8] = {h0.x,h0.y,h0.z,h0.w,h1.x,h1.y,h1.z,h1.w};
        const unsigned ll[8] = {l0.x,l0.y,l0.z,l0.w,l1.x,l1.y,l1.z,l1.w};
        #pragma unroll
        for (int e = 0; e < 8; ++e) {
            const float va = bf_lo(hh[e]) + bf_lo(ll[e]);
            const float vb = bf_hi(hh[e]) + bf_hi(ll[e]);
            s = fmaf(va, va, s); s = fmaf(vb, vb, s);
        }
        s += __shfl_xor(s, 1);
        s += __shfl_xor(s, 2);
        if (cq == 0) sqs[r] = s;
        __syncthreads();
    }

    // ================= 3 conv layers =================
    #pragma unroll 1
    for (int L = 0; L < 3; ++L) {
        const unsigned short* wpl = wp + L*16384;
        const float* bcl = (L == 0) ? bc1 : (L == 1) ? bc2 : bc3;

        // ---- Gram rounds + batched-bitonic top-k ----
        unsigned xk[32];
        #pragma unroll
        for (int s = 0; s < 24; ++s) xk[s] = 0xFFFFFFFFu;

        #pragma unroll 1
        for (int jt = 0; jt < 4; ++jt) {
            if (wg == (jt & 1)) {
                floatx16 acc = {0.f,0.f,0.f,0.f,0.f,0.f,0.f,0.f,0.f,0.f,0.f,0.f,0.f,0.f,0.f,0.f};
                #pragma unroll
                for (int p = 0; p < 3; ++p) {
                    const int aSel = (p == 2) ? 8 : 0;
                    const int bSel = (p == 1) ? 8 : 0;
                    short8 af[4], bf4[4];
                    #pragma unroll
                    for (int c = 0; c < 4; ++c) {
                        af[c]  = *(const short8*)hchunk(hilo, rt*32 + lj, aSel + c*2 + half);
                        bf4[c] = *(const short8*)hchunk(hilo, jt*32 + lj, bSel + c*2 + half);
                    }
                    #pragma unroll
                    for (int c = 0; c < 4; ++c) acc = __builtin_amdgcn_mfma_f32_32x32x16_bf16(af[c], bf4[c], acc, 0, 0, 0);
                }
                const unsigned jg = (unsigned)(jt*32 + lj);
                const float sqj = sqs[jg];
                #pragma unroll
                for (int reg = 0; reg < 16; ++reg) {
                    const int i = (reg & 3) + 8*(reg >> 2) + 4*half + rt*32;
                    float d = fmaf(-2.0f, acc[reg], sqs[i] + sqj);
                    d = fmaxf(d, 0.0f);
                    keys[i*34 + lj] = (__float_as_uint(d) & 0xFFFFFF80u) | jg;
                }
            }
            __syncthreads();
            {
                const unsigned* kr = keys + i2*34 + s4*8;
                const uint4 k0 = *(const uint4*)kr;
                const uint4 k1 = *(const uint4*)(kr + 4);
                unsigned y[8] = {k0.x, k0.y, k0.z, k0.w, k1.x, k1.y, k1.z, k1.w};
                sort8_asc(y);
                #pragma unroll
                for (int e = 0; e < 8; ++e) xk[24+e] = y[7-e];
                merge_top24(xk);
            }
            __syncthreads();
        }

        // ---- merge the 4 per-row lists into s4==0, emit nnidx ----
        #pragma unroll 1
        for (int src = 1; src < 4; ++src) {
            if (s4 == src) {
                #pragma unroll
                for (int e = 0; e < 24; ++e) keys[i2*34 + 8 + e] = xk[e];
            }
            __syncthreads();
            if (s4 == 0) {
                #pragma unroll 1
                for (int b = 0; b < 3; ++b) {
                    #pragma unroll
                    for (int e = 0; e < 8; ++e) xk[24+e] = keys[i2*34 + 8 + b*8 + (7-e)];
                    merge_top24(xk);
                }
            }
            __syncthreads();
        }
        if (s4 == 0) {
            #pragma unroll
            for (int c = 0; c < 6; ++c)
                nnidx[i2*6 + c] = (xk[c*4] & 127u) | ((xk[c*4+1] & 127u) << 8)
                                | ((xk[c*4+2] & 127u) << 16) | ((xk[c*4+3] & 127u) << 24);
        }
        __syncthreads();   // keys dead -> bs may overwrite; nnidx visible

        // ---- ab-GEMM: waves 0-3 -> a (global, +bias), waves 4-7 -> b (LDS bf16 [128][64]) ----
        unsigned short* bs = (unsigned short*)arena;
        {
            short8 afr[8];
            #pragma unroll
            for (int sel = 0; sel < 2; ++sel)
                #pragma unroll
                for (int c = 0; c < 4; ++c)
                    afr[sel*4+c] = *(const short8*)hchunk(hilo, rt*32 + lj, sel*8 + c*2 + half);

            #pragma unroll 1
            for (int q2 = 0; q2 < 2; ++q2) {
                const int jt = wg*2 + q2;
                short8 bfr[8];
                #pragma unroll
                for (int part = 0; part < 2; ++part)
                    #pragma unroll
                    for (int c = 0; c < 4; ++c)
                        bfr[part*4+c] = *(const short8*)((const short*)wpl + part*8192 + (((c*2 + half)*128) + jt*32 + lj)*8);
                floatx16 acc = {0.f,0.f,0.f,0.f,0.f,0.f,0.f,0.f,0.f,0.f,0.f,0.f,0.f,0.f,0.f,0.f};
                #pragma unroll
                for (int c = 0; c < 4; ++c) acc = __builtin_amdgcn_mfma_f32_32x32x16_bf16(afr[c],   bfr[c],   acc, 0, 0, 0);
                #pragma unroll
                for (int c = 0; c < 4; ++c) acc = __builtin_amdgcn_mfma_f32_32x32x16_bf16(afr[c],   bfr[4+c], acc, 0, 0, 0);
                #pragma unroll
                for (int c = 0; c < 4; ++c) acc = __builtin_amdgcn_mfma_f32_32x32x16_bf16(afr[4+c], bfr[c],   acc, 0, 0, 0);

                if (wg == 0) {
                    const int col = jt*32 + lj;
                    const float bias = bcl[col];
                    #pragma unroll
                    for (int reg = 0; reg < 16; ++reg) {
                        const int row = (reg & 3) + 8*(reg >> 2) + 4*half + rt*32;
                        ag[(size_t)row*64 + col] = acc[reg] + bias;
                    }
                } else {
                    const int colb = q2*32 + lj;
                    #pragma unroll
                    for (int reg = 0; reg < 16; ++reg) {
                        const int row = (reg & 3) + 8*(reg >> 2) + 4*half + rt*32;
                        bs[row*64 + colb] = bf_rne(acc[reg]);
                    }
                }
            }
        }
        __syncthreads();   // bs/ag ready; hilo reads done -> may be rewritten

        // ---- aggregation: out = elu(a + max_nn b); emit next hilo+sq, or pooled on last layer ----
        // lane = (rsub 0..7) x (fq 0..7): 8 rows/wave/iter, 8 features per lane (one uint4 per nbr)
        {
            const int rsub = lane >> 3, fq = lane & 7;
            float psum[8] = {0.f,0.f,0.f,0.f,0.f,0.f,0.f,0.f};
            #pragma unroll 1
            for (int it = 0; it < 2; ++it) {
                const int row = w*16 + it*8 + rsub;
                float m[8];
                #pragma unroll
                for (int e = 0; e < 8; ++e) m[e] = -3e38f;
                #pragma unroll
                for (int c = 0; c < 6; ++c) {
                    const unsigned pk = nnidx[row*6 + c];
                    #pragma unroll
                    for (int e2 = 0; e2 < 4; ++e2) {
                        const int j = (pk >> (8*e2)) & 127;
                        const uint4 bb = *(const uint4*)(bs + j*64 + fq*8);
                        m[0] = fmaxf(m[0], bf_lo(bb.x)); m[1] = fmaxf(m[1], bf_hi(bb.x));
                        m[2] = fmaxf(m[2], bf_lo(bb.y)); m[3] = fmaxf(m[3], bf_hi(bb.y));
                        m[4] = fmaxf(m[4], bf_lo(bb.z)); m[5] = fmaxf(m[5], bf_hi(bb.z));
                        m[6] = fmaxf(m[6], bf_lo(bb.w)); m[7] = fmaxf(m[7], bf_hi(bb.w));
                    }
                }
                const float4 a0 = *(const float4*)(ag + (size_t)row*64 + fq*8);
                const float4 a1 = *(const float4*)(ag + (size_t)row*64 + fq*8 + 4);
                float o[8];
                o[0] = elu_f(a0.x + m[0]); o[1] = elu_f(a0.y + m[1]);
                o[2] = elu_f(a0.z + m[2]); o[3] = elu_f(a0.w + m[3]);
                o[4] = elu_f(a1.x + m[4]); o[5] = elu_f(a1.y + m[5]);
                o[6] = elu_f(a1.z + m[6]); o[7] = elu_f(a1.w + m[7]);

                if (L < 2) {
                    unsigned hu[4], lu[4];
                    #pragma unroll
                    for (int e = 0; e < 4; ++e) {
                        unsigned short h0, l0, h1, l1;
                        split_bf16(o[2*e], h0, l0); split_bf16(o[2*e+1], h1, l1);
                        hu[e] = (unsigned)h0 | ((unsigned)h1 << 16);
                        lu[e] = (unsigned)l0 | ((unsigned)l1 << 16);
                    }
                    *(uint4*)hchunk(hilo, row, fq)     = make_uint4(hu[0], hu[1], hu[2], hu[3]);
                    *(uint4*)hchunk(hilo, row, 8 + fq) = make_uint4(lu[0], lu[1], lu[2], lu[3]);
                    float sp = 0.f;
                    #pragma unroll
                    for (int e = 0; e < 8; ++e) sp = fmaf(o[e], o[e], sp);
                    sp += __shfl_xor(sp, 1);
                    sp += __shfl_xor(sp, 2);
                    sp += __shfl_xor(sp, 4);
                    if (fq == 0) sqs[row] = sp;
                } else {
                    #pragma unroll
                    for (int e = 0; e < 8; ++e) psum[e] += o[e];
                }
            }
            if (L < 2) {
                __syncthreads();   // next layer sees new hilo + sqs
            } else {
                // reduce over rows (lanes with same fq): xor 8,16,32
                #pragma unroll
                for (int e = 0; e < 8; ++e) {
                    psum[e] += __shfl_xor(psum[e], 8);
                    psum[e] += __shfl_xor(psum[e], 16);
                    psum[e] += __shfl_xor(psum[e], 32);
                }
                __syncthreads();   // nnidx reads done -> pool8 may alias
                float* pool8 = (float*)(arena + 17408);   // [8][64]
                if (rsub == 0) {
                    *(float4*)(pool8 + w*64 + fq*8)     = make_float4(psum[0], psum[1], psum[2], psum[3]);
                    *(float4*)(pool8 + w*64 + fq*8 + 4) = make_float4(psum[4], psum[5], psum[6], psum[7]);
                }
                __syncthreads();
                if (t < 64) {
                    float s = 0.0f;
                    #pragma unroll
                    for (int k = 0; k < 8; ++k) s += pool8[k*64 + t];
                    pooled_out[(size_t)g*64 + t] = s;
                }
            }
        }
    }
}

// ---------------- head: 5-layer MLP on pooled[512][64] ----------------
__global__ __launch_bounds__(64) void head_kernel(
    const float* __restrict__ pooled_in,
    const float* __restrict__ wo1, const float* __restrict__ bo1,
    const float* __restrict__ wo2, const float* __restrict__ bo2,
    const float* __restrict__ wo3, const float* __restrict__ bo3,
    const float* __restrict__ wo4, const float* __restrict__ bo4,
    const float* __restrict__ wo5, const float* __restrict__ bo5,
    float* __restrict__ outp)
{
    __shared__ float pooled[64];
    __shared__ float o1[64];
    __shared__ float o2[32];
    __shared__ float o3[32];
    __shared__ float o4[8];
    const int g = blockIdx.x, t = threadIdx.x;

    pooled[t] = pooled_in[(size_t)g*64 + t];
    {
        float acc = bo1[t];
        #pragma unroll
        for (int k = 0; k < 64; ++k) acc = fmaf(pooled[k], wo1[k*64 + t], acc);
        o1[t] = elu_f(acc);
    }
    if (t < 32) {
        float acc = bo2[t];
        #pragma unroll
        for (int k = 0; k < 64; ++k) acc = fmaf(o1[k], wo2[k*32 + t], acc);
        o2[t] = elu_f(acc);
    }
    if (t < 32) {
        float acc = bo3[t];
        #pragma unroll
        for (int k = 0; k < 32; ++k) acc = fmaf(o2[k], wo3[k*32 + t], acc);
        o3[t] = elu_f(acc);
    }
    if (t < 8) {
        float acc = bo4[t];
        #pragma unroll
        for (int k = 0; k < 32; ++k) acc = fmaf(o3[k], wo4[k*8 + t], acc);
        o4[t] = elu_f(acc);
    }
    if (t == 0) {
        float acc = bo5[0];
        #pragma unroll
        for (int k = 0; k < 8; ++k) acc = fmaf(o4[k], wo5[k], acc);
        outp[g] = acc;
    }
}

extern "C" void kernel_launch(void* const* d_in, const int* in_sizes, int n_in,
                              void* d_out, int out_size, void* d_ws, size_t ws_size,
                              hipStream_t stream) {
    const float* x_pf = (const float*)d_in[0];
    const float* we1 = (const float*)d_in[2];
    const float* be1 = (const float*)d_in[3];
    const float* we2 = (const float*)d_in[4];
    const float* be2 = (const float*)d_in[5];
    const float* wc1 = (const float*)d_in[6];
    const float* bc1 = (const float*)d_in[7];
    const float* wc2 = (const float*)d_in[8];
    const float* bc2 = (const float*)d_in[9];
    const float* wc3 = (const float*)d_in[10];
    const float* bc3 = (const float*)d_in[11];
    const float* wo1 = (const float*)d_in[12];
    const float* bo1 = (const float*)d_in[13];
    const float* wo2 = (const float*)d_in[14];
    const float* bo2 = (const float*)d_in[15];
    const float* wo3 = (const float*)d_in[16];
    const float* bo3 = (const float*)d_in[17];
    const float* wo4 = (const float*)d_in[18];
    const float* bo4 = (const float*)d_in[19];
    const float* wo5 = (const float*)d_in[20];
    const float* bo5 = (const float*)d_in[21];

    float* out = (float*)d_out;           // [0:512) outputs, [512:) batch ids (as float)
    char* ws = (char*)d_ws;
    float* abuf   = (float*)(ws);                                  // 16 MB
    float* pooled = (float*)(ws + (size_t)16*1024*1024);           // 128 KB
    unsigned short* wpack = (unsigned short*)(ws + (size_t)17*1024*1024);  // 112 KB

    pack_w<<<112, 256, 0, stream>>>(wc1, wc2, wc3, we2, wpack);

    conv_all<<<NG, 512, 0, stream>>>(x_pf, wpack, bc1, bc2, bc3,
        we1, be1, wpack + 49152, be2, abuf, pooled, out + NG);

    head_kernel<<<NG, 64, 0, stream>>>(pooled, wo1, bo1, wo2, bo2, wo3, bo3, wo4, bo4, wo5, bo5, out);
}